// Round 1
// baseline (304.953 us; speedup 1.0000x reference)
//
#include <hip/hip_runtime.h>

// CSTR gated-estimator trajectory cost.
// B=8192 samples, N=2 states, T=2048 sequential RK4 steps.
// Parallelism: 1 thread per sample (8192 threads = 128 waves). The scan is
// sequential+nonlinear -> no time parallelism. Whole kernel is latency/issue
// bound on 128 resident waves; minimize per-step instruction count.

#define T_STEPS 2048
#define BATCH   8192

__global__ __launch_bounds__(64, 1) void cstr_kernel(
    const float* __restrict__ w,   // (B, 2, T)
    const float* __restrict__ K,   // (1, 2)
    const float* __restrict__ L,   // (4, 4)
    const float* __restrict__ M,   // (1, 4)
    const float* __restrict__ Mo,  // (1, 1)
    float* __restrict__ out)       // (B,)
{
    const int b = blockIdx.x * 64 + threadIdx.x;

    // ---- uniform constants (per-thread loads, one-time, L2-broadcast) ----
    const float k1c = K[0], k2c = K[1];
    // symmetrized quadratic coefficients: z^T L z = sum_{i<=j} s_ij z_i z_j
    const float s11 = L[0];
    const float s12 = L[1] + L[4];
    const float s13 = L[2] + L[8];
    const float s14 = L[3] + L[12];
    const float s22 = L[5];
    const float s23 = L[6] + L[9];
    const float s24 = L[7] + L[13];
    const float s33 = L[10];
    const float s34 = L[11] + L[14];
    const float s44 = L[15];
    const float m1 = M[0], m2 = M[1], m3 = M[2], m4 = M[3];
    const float c0 = Mo[0];

    // RK4 with affine plant + constant stage offsets collapses analytically:
    // k1+4k2+k4 = 6*k1 + [3H, -6H]  =>
    //   x1' = (1-2H)x1 + H*x2 + H*u + H^2/2 + w1
    //   x2' = H*x1 + (1-2H)x2 + H*u - H^2   + w2
    constexpr float Hs = 0.01f;
    constexpr float Ad = 1.0f - 2.0f * Hs;   // 0.98
    constexpr float C1 = 0.5f * Hs * Hs;     // +H^2/2
    constexpr float C2 = -Hs * Hs;           // -H^2
    constexpr float Rc = 0.1f;

    const float4* r0 = reinterpret_cast<const float4*>(w + (size_t)b * (2 * T_STEPS));
    const float4* r1 = r0 + (T_STEPS / 4);   // second state row, 2048 floats later

    float x1 = 1.0f, x2 = 0.0f, xh1 = 1.0f, xh2 = 0.0f, acc = 0.0f;

    auto step = [&](float w1, float w2, bool first, bool last) {
        float delta;
        if (first) {
            delta = 1.0f;                       // i==0: gate forced open, x_hat unchanged
        } else {
            // phi = c0 + m.z + z^T S z   (14 fma)
            float t1 = fmaf(s14, xh2, fmaf(s13, xh1, fmaf(s12, x2, fmaf(s11, x1, m1))));
            float t2 = fmaf(s24, xh2, fmaf(s23, xh1, fmaf(s22, x2, m2)));
            float t3 = fmaf(s34, xh2, fmaf(s33, xh1, m3));
            float t4 = fmaf(s44, xh2, m4);
            float phi = fmaf(xh2, t4, fmaf(xh1, t3, fmaf(x2, t2, fmaf(x1, t1, c0))));
            // sigmoid: v_exp + v_rcp (no div sequence)
            float e = __expf(-phi);
            delta = __builtin_amdgcn_rcpf(1.0f + e);
            xh1 = fmaf(delta, x1 - xh1, xh1);
            xh2 = fmaf(delta, x2 - xh2, xh2);
        }
        float u = fmaf(k1c, xh1, k2c * xh2);    // control from gated estimate
        if (!last) {                             // scs[:T-1]
            float us = fmaf(k1c, x1, k2c * x2);  // J uses K @ x (pre-update)
            acc = fmaf(x1, x1, acc);
            acc = fmaf(x2, x2, acc);
            acc = fmaf(Rc * us, us, acc);
            acc += delta;
        }
        float nx1 = fmaf(Ad, x1, fmaf(Hs, x2, fmaf(Hs, u, w1 + C1)));
        float nx2 = fmaf(Hs, x1, fmaf(Ad, x2, fmaf(Hs, u, w2 + C2)));
        x1 = nx1; x2 = nx2;
    };

    // 16-step chunk from register buffers
    auto chunk = [&](const float4* b0, const float4* b1, bool first, bool last) {
        #pragma unroll
        for (int q = 0; q < 4; ++q) {
            float4 a = b0[q], c = b1[q];
            step(a.x, c.x, first && (q == 0), false);
            step(a.y, c.y, false, false);
            step(a.z, c.z, false, false);
            step(a.w, c.w, false, last && (q == 3));
        }
    };

    // double-buffered register streaming: prefetch distance = 1 chunk
    // (16 steps ~ 1400 cyc of compute in flight vs ~900 cyc HBM latency)
    float4 A0[4], A1[4], B0[4], B1[4];
    #pragma unroll
    for (int q = 0; q < 4; ++q) { A0[q] = r0[q]; A1[q] = r1[q]; }

    for (int ci = 0; ci < 128; ci += 2) {
        {   // prefetch chunk ci+1
            const float4* p0 = r0 + (size_t)(ci + 1) * 4;
            const float4* p1 = r1 + (size_t)(ci + 1) * 4;
            #pragma unroll
            for (int q = 0; q < 4; ++q) { B0[q] = p0[q]; B1[q] = p1[q]; }
        }
        chunk(A0, A1, ci == 0, false);
        if (ci + 2 < 128) {   // prefetch chunk ci+2
            const float4* p0 = r0 + (size_t)(ci + 2) * 4;
            const float4* p1 = r1 + (size_t)(ci + 2) * 4;
            #pragma unroll
            for (int q = 0; q < 4; ++q) { A0[q] = p0[q]; A1[q] = p1[q]; }
        }
        chunk(B0, B1, false, ci + 2 >= 128);
    }

    // terminal cost: x_T @ (10 I) @ x_T
    out[b] = fmaf(10.0f, fmaf(x1, x1, x2 * x2), acc);
}

extern "C" void kernel_launch(void* const* d_in, const int* in_sizes, int n_in,
                              void* d_out, int out_size, void* d_ws, size_t ws_size,
                              hipStream_t stream) {
    const float* w  = (const float*)d_in[0];
    const float* K  = (const float*)d_in[1];
    const float* L  = (const float*)d_in[2];
    const float* M  = (const float*)d_in[3];
    const float* Mo = (const float*)d_in[4];
    float* out = (float*)d_out;

    hipLaunchKernelGGL(cstr_kernel, dim3(BATCH / 64), dim3(64), 0, stream,
                       w, K, L, M, Mo, out);
}

// Round 2
// 303.339 us; speedup vs baseline: 1.0053x; 1.0053x over previous
//
#include <hip/hip_runtime.h>

// CSTR gated-estimator trajectory cost — 2 lanes per sample.
// B=8192 samples, T=2048 sequential RK4 steps, N=2 states.
// Lane parity p = state index. Lane owns (x_p, xh_p); partner values come via
// DPP quad_perm swap (lanes 2i <-> 2i+1). This doubles wave count 128 -> 256
// (256 SIMDs engaged instead of 128) and halves per-wave issue per step.
// RK4 collapsed analytically (affine plant):
//   x_own' = (1-2H) x_own + H x_other + H u + C_own + w_own,
//   C_1 = +H^2/2, C_2 = -H^2  (plant is symmetric under 1<->2 swap).
// Sigmoid argument folded into exp2 domain: all phi coefficients pre-scaled
// by -log2(e), so sigma = rcp(1 + v_exp(partial_A + partial_B)).

#define T_STEPS 2048
#define BATCH   8192

__device__ __forceinline__ float swapf(float v) {
    // quad_perm [1,0,3,2]: swap adjacent lane pairs. bound_ctrl=1, full masks.
    return __int_as_float(__builtin_amdgcn_update_dpp(
        0, __float_as_int(v), 0xB1, 0xF, 0xF, true));
}

__global__ __launch_bounds__(64, 1) void cstr_kernel(
    const float* __restrict__ w,   // (B, 2, T)
    const float* __restrict__ K,   // (1, 2)
    const float* __restrict__ L,   // (4, 4)
    const float* __restrict__ M,   // (1, 4)
    const float* __restrict__ Mo,  // (1, 1)
    float* __restrict__ out)       // (B,)
{
    const int lane = threadIdx.x;
    const int p = lane & 1;                          // owned state index
    const int s = blockIdx.x * 32 + (lane >> 1);     // sample id

    // ---- uniform scalars ----
    const float k1c = K[0], k2c = K[1];
    const float s11 = L[0];
    const float s12 = L[1] + L[4];
    const float s13 = L[2] + L[8];
    const float s14 = L[3] + L[12];
    const float s22 = L[5];
    const float s23 = L[6] + L[9];
    const float s24 = L[7] + L[13];
    const float s33 = L[10];
    const float s34 = L[11] + L[14];
    const float s44 = L[15];
    const float m1 = M[0], m2 = M[1], m3 = M[2], m4 = M[3];
    const float c0 = Mo[0];

    constexpr float Hs = 0.01f;
    constexpr float Ad = 1.0f - 2.0f * Hs;           // 0.98
    constexpr float Rc = 0.1f;
    constexpr float SC = -1.44269504088896340736f;   // -log2(e)

    // ---- per-lane constants ----
    // phi partial (lane-generic):
    //   part = x*(P1*x + P2*xo + P3*xh + P4*xho + P5) + xh*(P6*xh + P7*xho + P8) + P9
    // lane0 (own=1): terms s11,s12,s13,s14,m1,s33,s34,m3 ; lane1 (own=2): s22,s24,s23,m2,s44,m4
    float P1, P2, P3, P4, P5, P6, P7, P8;
    if (p == 0) { P1 = s11; P2 = s12; P3 = s13; P4 = s14; P5 = m1; P6 = s33; P7 = s34; P8 = m3; }
    else        { P1 = s22; P2 = 0.f; P3 = s24; P4 = s23; P5 = m2; P6 = s44; P7 = 0.f; P8 = m4; }
    P1 *= SC; P2 *= SC; P3 *= SC; P4 *= SC; P5 *= SC; P6 *= SC; P7 *= SC; P8 *= SC;
    const float P9 = 0.5f * c0 * SC;

    const float kown = p ? k2c : k1c;
    const float koth = p ? k1c : k2c;
    const float hk   = Hs * kown;                     // H * K_own for hu
    const float Cown = p ? (-Hs * Hs) : (0.5f * Hs * Hs);

    // ---- state ----
    float x   = p ? 0.0f : 1.0f;   // x0 = (1, 0)
    float xh  = x;
    float accO = 0.0f;             // sum of own-state x^2 (split across pair)
    float accD = 0.0f;             // duplicated: sum of Rc*us^2 + delta

    // one generic step; `first`/`cost` are always literal at call sites
    auto step = [&](float wv, bool first, bool cost) {
        float xo  = swapf(x);
        float xho = swapf(xh);
        float d;
        if (first) {
            d = 1.0f;              // i==0: gate forced, x_hat frozen (x==xh anyway)
        } else {
            float t  = fmaf(P2, xo, fmaf(P1, x, P5));
            t        = fmaf(P3, xh, t);
            t        = fmaf(P4, xho, t);
            float u2 = fmaf(P7, xho, fmaf(P6, xh, P8));
            float part = fmaf(xh, u2, fmaf(x, t, P9));
            float e  = __builtin_amdgcn_exp2f(part + swapf(part)); // = exp(-phi)
            d        = __builtin_amdgcn_rcpf(1.0f + e);
            xh       = fmaf(d, x - xh, xh);
        }
        if (cost) {                 // stage cost uses PRE-update x and this step's delta
            float us = fmaf(kown, x, koth * xo);
            accO = fmaf(x, x, accO);
            accD = fmaf(Rc * us, us, accD);
            accD += d;
        }
        float pown = hk * xh;       // H*u split: hu = H*(k1*xh1' + k2*xh2')
        float hu   = pown + swapf(pown);
        x = fmaf(Ad, x, fmaf(Hs, xo, wv + Cown)) + hu;
    };

    auto chunk = [&](const float4* buf, bool first, bool lastchunk) {
        #pragma unroll
        for (int q = 0; q < 4; ++q) {
            float4 a = buf[q];
            step(a.x, first && (q == 0), true);
            step(a.y, false, true);
            step(a.z, false, true);
            step(a.w, false, !(lastchunk && (q == 3)));  // t=T-1: no stage cost
        }
    };

    // own-row stream: T floats = 512 float4 = 128 chunks of 16 steps
    const float4* r = reinterpret_cast<const float4*>(
        w + ((size_t)s * 2 + p) * T_STEPS);

    float4 Abuf[4], Bbuf[4];
    #pragma unroll
    for (int q = 0; q < 4; ++q) Abuf[q] = r[q];        // chunk 0
    #pragma unroll
    for (int q = 0; q < 4; ++q) Bbuf[q] = r[4 + q];    // chunk 1

    chunk(Abuf, true, false);                          // chunk 0 (step 0 special)

    for (int i = 0; i < 63; ++i) {                     // chunks 1..126
        const float4* pa = r + (size_t)(2 + 2 * i) * 4;
        #pragma unroll
        for (int q = 0; q < 4; ++q) Abuf[q] = pa[q];   // prefetch chunk 2+2i
        chunk(Bbuf, false, false);                     // process chunk 1+2i
        const float4* pb = r + (size_t)(3 + 2 * i) * 4;
        #pragma unroll
        for (int q = 0; q < 4; ++q) Bbuf[q] = pb[q];   // prefetch chunk 3+2i (<=127)
        chunk(Abuf, false, false);                     // process chunk 2+2i
    }
    chunk(Bbuf, false, true);                          // chunk 127 (last step: no cost)

    // terminal cost 10*(x1^2 + x2^2), split by ownership
    accO = fmaf(10.0f * x, x, accO);
    float J = accO + swapf(accO) + accD;
    if (p == 0) out[s] = J;
}

extern "C" void kernel_launch(void* const* d_in, const int* in_sizes, int n_in,
                              void* d_out, int out_size, void* d_ws, size_t ws_size,
                              hipStream_t stream) {
    const float* w  = (const float*)d_in[0];
    const float* K  = (const float*)d_in[1];
    const float* L  = (const float*)d_in[2];
    const float* M  = (const float*)d_in[3];
    const float* Mo = (const float*)d_in[4];
    float* out = (float*)d_out;

    // 8192 samples * 2 lanes = 16384 threads = 256 blocks of 64 (1 wave each)
    hipLaunchKernelGGL(cstr_kernel, dim3(BATCH * 2 / 64), dim3(64), 0, stream,
                       w, K, L, M, Mo, out);
}